// Round 4
// baseline (1201.618 us; speedup 1.0000x reference)
//
#include <hip/hip_runtime.h>
#include <math.h>

#define VB 28
#define LL 64
#define PAD_TOK 26
#define EOS_TOK 27
#define NSLOT 34   // 0 loss,1 mask,2 consec,3 mexp,4 kl,5 cls,6..33 vocab
#define REPL 8     // replicated atomic banks, stride 64 floats

// compile-time (k+1)^2.5 via constexpr Newton sqrt -> folds to inline literals
constexpr double csqrt_(double x) {
  double g = x > 1.0 ? x : 1.0;
  for (int i = 0; i < 60; ++i) g = 0.5 * (g + x / g);
  return g;
}
constexpr float wp(int k) {  // weight for window step k (window len k+1)
  double n = (double)(k + 1);
  return (float)(n * n * csqrt_(n));
}

__device__ __forceinline__ float wave_red(float v) {
  #pragma unroll
  for (int o = 32; o > 0; o >>= 1) v += __shfl_down(v, o, 64);
  return v;
}

__global__ __launch_bounds__(256) void vae_main(
    const float* __restrict__ x, const float* __restrict__ rec,
    const float* __restrict__ zm, const float* __restrict__ zlv,
    const float* __restrict__ cs, float* __restrict__ ws,
    int nrows, int nz, int nc, int nblocks) {
  __shared__ float adj_s[4][128];
  __shared__ float red[4][NSLOT];
  const int lane = threadIdx.x & 63;
  const int wid  = threadIdx.x >> 6;
  adj_s[wid][64 + lane] = 0.f;   // zero pad; reads reach at most index 125
  __builtin_amdgcn_wave_barrier();  // keep pad-write ahead of any adj reads

  float loss_acc = 0.f, mask_cnt = 0.f, mexp_cnt = 0.f;
  float consec0 = 0.f, consec1 = 0.f;
  float vocab[VB];
  #pragma unroll
  for (int v = 0; v < VB; ++v) vocab[v] = 0.f;

  const int wave_id = blockIdx.x * 4 + wid;
  const int n_waves = nblocks * 4;

  for (int row = wave_id; row < nrows; row += n_waves) {
    const size_t base = ((size_t)row * LL + lane) * VB;
    const float4* xp = reinterpret_cast<const float4*>(x + base);
    const float4* rp = reinterpret_cast<const float4*>(rec + base);
    float r[VB];
    float best = -INFINITY, pt = 0.f;
    int tgt = 0;
    #pragma unroll
    for (int i = 0; i < 7; ++i) {
      float4 xq = xp[i];
      float4 rq = rp[i];
      r[i*4+0] = rq.x; r[i*4+1] = rq.y; r[i*4+2] = rq.z; r[i*4+3] = rq.w;
      if (xq.x > best) { best = xq.x; tgt = i*4+0; pt = rq.x; }
      if (xq.y > best) { best = xq.y; tgt = i*4+1; pt = rq.y; }
      if (xq.z > best) { best = xq.z; tgt = i*4+2; pt = rq.z; }
      if (xq.w > best) { best = xq.w; tgt = i*4+3; pt = rq.w; }
    }
    const float mask = (tgt != PAD_TOK) ? 1.f : 0.f;
    const float mexp = (tgt != PAD_TOK && tgt != EOS_TOK) ? 1.f : 0.f;
    loss_acc += -__logf(fminf(fmaxf(pt, 1e-7f), 1.f)) * mask;
    mask_cnt += mask;
    mexp_cnt += mexp;
    #pragma unroll
    for (int v = 0; v < VB; ++v) vocab[v] += r[v] * mexp;

    // adjacent[j] = dot(recon[:,j], recon[:,j+1]) * (target[j+1] != PAD)
    float adj = 0.f;
    #pragma unroll
    for (int v = 0; v < VB; ++v) adj += r[v] * __shfl_down(r[v], 1, 64);
    const int tgt_next = __shfl_down(tgt, 1, 64);
    adj = (lane < 63 && tgt_next != PAD_TOK) ? adj : 0.f;

    // stage adjacent in this wave's LDS row. Cross-lane via LDS needs
    // compiler fences: per-thread alias analysis proves lane != lane+k and
    // would otherwise hoist the reads above the write (round-3 bug).
    __builtin_amdgcn_wave_barrier();   // don't sink write below prior reads
    adj_s[wid][lane] = adj;
    __builtin_amdgcn_wave_barrier();   // don't hoist reads above write

    // lane j: sum_k (k+1)^2.5 * prod(adj[j..j+k]). Pad zeros kill windows
    // that cross the end; underflowed products stay exactly 0 (harmless).
    // No ballot: pure pipelined ds_read+mul+fma, no wave-wide sync points.
    const float* ap = &adj_s[wid][lane];
    float p = adj;
    consec0 += p;                      // k=0, weight 1
    #pragma unroll
    for (int k = 1; k <= 62; k += 2) {
      p *= ap[k];
      consec1 += wp(k) * p;
      if (k + 1 <= 62) {
        p *= ap[k + 1];
        consec0 += wp(k + 1) * p;
      }
    }
    __builtin_amdgcn_wave_barrier();   // next row's write must not pass reads
  }
  float consec_acc = consec0 + consec1;

  // KL + classifier terms, grid-strided over all threads
  const int gid = blockIdx.x * 256 + threadIdx.x;
  const int gstride = nblocks * 256;
  float kl = 0.f, cl = 0.f;
  for (int i = gid; i < nz; i += gstride) {
    const float m = zm[i], lv = zlv[i];
    kl += 1.f + lv - m * m - __expf(lv);
  }
  for (int i = gid; i < nc; i += gstride) cl += __logf(cs[i] + 1e-7f);

  loss_acc   = wave_red(loss_acc);
  mask_cnt   = wave_red(mask_cnt);
  consec_acc = wave_red(consec_acc);
  mexp_cnt   = wave_red(mexp_cnt);
  kl         = wave_red(kl);
  cl         = wave_red(cl);
  #pragma unroll
  for (int v = 0; v < VB; ++v) vocab[v] = wave_red(vocab[v]);

  if (lane == 0) {
    red[wid][0] = loss_acc; red[wid][1] = mask_cnt;
    red[wid][2] = consec_acc; red[wid][3] = mexp_cnt;
    red[wid][4] = kl; red[wid][5] = cl;
    #pragma unroll
    for (int v = 0; v < VB; ++v) red[wid][6 + v] = vocab[v];
  }
  __syncthreads();
  if (threadIdx.x < NSLOT) {   // fire-and-forget: no fence, no wait
    const int t = threadIdx.x;
    float* bank = ws + ((blockIdx.x & (REPL - 1)) << 6);
    atomicAdd(&bank[t], red[0][t] + red[1][t] + red[2][t] + red[3][t]);
  }
}

__global__ void vae_finalize(const float* __restrict__ ws, float* __restrict__ out,
                             float nz, float nc) {
  if (threadIdx.x == 0 && blockIdx.x == 0) {
    const float freqs[VB] = {0.0817f,0.0149f,0.0278f,0.0425f,0.127f,0.0223f,
      0.0202f,0.0609f,0.0697f,0.0015f,0.0077f,0.0403f,0.0241f,0.0675f,0.0751f,
      0.0193f,0.001f,0.0599f,0.0633f,0.0906f,0.0276f,0.0098f,0.0236f,0.0015f,
      0.0197f,0.0007f,0.f,0.f};
    float fin[NSLOT];
    #pragma unroll
    for (int t = 0; t < NSLOT; ++t) {
      float s = 0.f;
      #pragma unroll
      for (int b = 0; b < REPL; ++b) s += ws[(b << 6) + t];
      fin[t] = s;
    }
    const float rec_loss = fin[0] / fin[1];
    const float kl_loss  = -0.5f * fin[4] / nz;
    const float cls_loss = -fin[5] / nc;
    const float inv_mexp = 1.f / fin[3];
    float fp = 0.f;
    #pragma unroll
    for (int v = 0; v < VB; ++v)
      fp += fmaxf(0.f, fin[6 + v] * inv_mexp - freqs[v]);
    out[0] = rec_loss + 0.1f * kl_loss + 2.f * cls_loss
           + 0.2f * fin[2] + 0.5f * fp;
  }
}

extern "C" void kernel_launch(void* const* d_in, const int* in_sizes, int n_in,
                              void* d_out, int out_size, void* d_ws, size_t ws_size,
                              hipStream_t stream) {
  const float* x   = (const float*)d_in[0];
  const float* rec = (const float*)d_in[1];
  const float* zm  = (const float*)d_in[2];
  const float* zlv = (const float*)d_in[3];
  const float* cs  = (const float*)d_in[4];
  float* out = (float*)d_out;
  float* ws  = (float*)d_ws;

  const int nrows = in_sizes[0] / (LL * VB);     // B
  const int nz    = in_sizes[2];                 // B * LATENT
  const int nc    = in_sizes[4];                 // B

  int nblocks = (nrows + 3) / 4;                 // 1 row per wave
  if (nblocks < 1) nblocks = 1;

  hipMemsetAsync(d_ws, 0, REPL * 64 * sizeof(float), stream);
  vae_main<<<nblocks, 256, 0, stream>>>(x, rec, zm, zlv, cs, ws,
                                        nrows, nz, nc, nblocks);
  vae_finalize<<<1, 64, 0, stream>>>(ws, out, (float)nz, (float)nc);
}

// Round 5
// 180.866 us; speedup vs baseline: 6.6437x; 6.6437x over previous
//
#include <hip/hip_runtime.h>
#include <math.h>

#define VB 28
#define LL 64
#define PAD_TOK 26
#define EOS_TOK 27
#define NSLOT 34   // 0 loss,1 mask,2 consec,3 mexp,4 kl,5 cls,6..33 vocab
#define REPL 8     // replicated atomic banks, stride 64 floats

// (k+1)^2.5 table. MUST be a constexpr VARIABLE: round-4 lesson — a constexpr
// function called at runtime context is legally emitted as runtime code, and
// the compiler ran 60 f64 Newton iterations per call (72% VALUBusy, 20x slow).
// constexpr-variable init is mandatory compile-time; post-unroll WTAB.w[k]
// folds to a float literal.
constexpr double csqrt_(double x) {
  double g = x > 1.0 ? x : 1.0;
  for (int i = 0; i < 60; ++i) g = 0.5 * (g + x / g);
  return g;
}
struct WTab { float w[64]; };
constexpr WTab make_wtab() {
  WTab t{};
  for (int k = 0; k < 64; ++k) {
    double n = (double)(k + 1);
    t.w[k] = (float)(n * n * csqrt_(n));   // (k+1)^2.5
  }
  return t;
}
constexpr WTab WTAB = make_wtab();

__device__ __forceinline__ float wave_red(float v) {
  #pragma unroll
  for (int o = 32; o > 0; o >>= 1) v += __shfl_down(v, o, 64);
  return v;
}

__global__ __launch_bounds__(256) void vae_main(
    const float* __restrict__ x, const float* __restrict__ rec,
    const float* __restrict__ zm, const float* __restrict__ zlv,
    const float* __restrict__ cs, float* __restrict__ ws,
    int nrows, int nz, int nc, int nblocks) {
  __shared__ float adj_s[4][128];
  __shared__ float red[4][NSLOT];
  const int lane = threadIdx.x & 63;
  const int wid  = threadIdx.x >> 6;
  adj_s[wid][64 + lane] = 0.f;   // zero pad; reads reach at most index 125
  __builtin_amdgcn_wave_barrier();  // keep pad-write ahead of any adj reads

  float loss_acc = 0.f, mask_cnt = 0.f, mexp_cnt = 0.f;
  float consec0 = 0.f, consec1 = 0.f;
  float vocab[VB];
  #pragma unroll
  for (int v = 0; v < VB; ++v) vocab[v] = 0.f;

  const int wave_id = blockIdx.x * 4 + wid;
  const int n_waves = nblocks * 4;

  for (int row = wave_id; row < nrows; row += n_waves) {
    const size_t base = ((size_t)row * LL + lane) * VB;
    const float4* xp = reinterpret_cast<const float4*>(x + base);
    const float4* rp = reinterpret_cast<const float4*>(rec + base);
    float r[VB];
    float best = -INFINITY, pt = 0.f;
    int tgt = 0;
    #pragma unroll
    for (int i = 0; i < 7; ++i) {
      float4 xq = xp[i];
      float4 rq = rp[i];
      r[i*4+0] = rq.x; r[i*4+1] = rq.y; r[i*4+2] = rq.z; r[i*4+3] = rq.w;
      if (xq.x > best) { best = xq.x; tgt = i*4+0; pt = rq.x; }
      if (xq.y > best) { best = xq.y; tgt = i*4+1; pt = rq.y; }
      if (xq.z > best) { best = xq.z; tgt = i*4+2; pt = rq.z; }
      if (xq.w > best) { best = xq.w; tgt = i*4+3; pt = rq.w; }
    }
    const float mask = (tgt != PAD_TOK) ? 1.f : 0.f;
    const float mexp = (tgt != PAD_TOK && tgt != EOS_TOK) ? 1.f : 0.f;
    loss_acc += -__logf(fminf(fmaxf(pt, 1e-7f), 1.f)) * mask;
    mask_cnt += mask;
    mexp_cnt += mexp;
    #pragma unroll
    for (int v = 0; v < VB; ++v) vocab[v] += r[v] * mexp;

    // adjacent[j] = dot(recon[:,j], recon[:,j+1]) * (target[j+1] != PAD)
    float adj = 0.f;
    #pragma unroll
    for (int v = 0; v < VB; ++v) adj += r[v] * __shfl_down(r[v], 1, 64);
    const int tgt_next = __shfl_down(tgt, 1, 64);
    adj = (lane < 63 && tgt_next != PAD_TOK) ? adj : 0.f;

    // stage adjacent in this wave's LDS row. Cross-lane via LDS needs
    // compiler fences: per-thread alias analysis proves lane != lane+k and
    // would otherwise hoist the reads above the write (round-3 bug).
    __builtin_amdgcn_wave_barrier();   // don't sink write below prior reads
    adj_s[wid][lane] = adj;
    __builtin_amdgcn_wave_barrier();   // don't hoist reads above write

    // lane j: sum_k (k+1)^2.5 * prod(adj[j..j+k]). Pad zeros kill windows
    // that cross the end; underflowed products stay exactly 0 (harmless).
    const float* ap = &adj_s[wid][lane];
    float p = adj;
    consec0 += p;                      // k=0, weight 1
    #pragma unroll
    for (int k = 1; k <= 62; k += 2) {
      p *= ap[k];
      consec1 += WTAB.w[k] * p;
      if (k + 1 <= 62) {
        p *= ap[k + 1];
        consec0 += WTAB.w[k + 1] * p;
      }
    }
    __builtin_amdgcn_wave_barrier();   // next row's write must not pass reads
  }
  float consec_acc = consec0 + consec1;

  // KL + classifier terms, grid-strided over all threads
  const int gid = blockIdx.x * 256 + threadIdx.x;
  const int gstride = nblocks * 256;
  float kl = 0.f, cl = 0.f;
  for (int i = gid; i < nz; i += gstride) {
    const float m = zm[i], lv = zlv[i];
    kl += 1.f + lv - m * m - __expf(lv);
  }
  for (int i = gid; i < nc; i += gstride) cl += __logf(cs[i] + 1e-7f);

  loss_acc   = wave_red(loss_acc);
  mask_cnt   = wave_red(mask_cnt);
  consec_acc = wave_red(consec_acc);
  mexp_cnt   = wave_red(mexp_cnt);
  kl         = wave_red(kl);
  cl         = wave_red(cl);
  #pragma unroll
  for (int v = 0; v < VB; ++v) vocab[v] = wave_red(vocab[v]);

  if (lane == 0) {
    red[wid][0] = loss_acc; red[wid][1] = mask_cnt;
    red[wid][2] = consec_acc; red[wid][3] = mexp_cnt;
    red[wid][4] = kl; red[wid][5] = cl;
    #pragma unroll
    for (int v = 0; v < VB; ++v) red[wid][6 + v] = vocab[v];
  }
  __syncthreads();
  if (threadIdx.x < NSLOT) {   // fire-and-forget: no fence, no wait
    const int t = threadIdx.x;
    float* bank = ws + ((blockIdx.x & (REPL - 1)) << 6);
    atomicAdd(&bank[t], red[0][t] + red[1][t] + red[2][t] + red[3][t]);
  }
}

__global__ void vae_finalize(const float* __restrict__ ws, float* __restrict__ out,
                             float nz, float nc) {
  if (threadIdx.x == 0 && blockIdx.x == 0) {
    const float freqs[VB] = {0.0817f,0.0149f,0.0278f,0.0425f,0.127f,0.0223f,
      0.0202f,0.0609f,0.0697f,0.0015f,0.0077f,0.0403f,0.0241f,0.0675f,0.0751f,
      0.0193f,0.001f,0.0599f,0.0633f,0.0906f,0.0276f,0.0098f,0.0236f,0.0015f,
      0.0197f,0.0007f,0.f,0.f};
    float fin[NSLOT];
    #pragma unroll
    for (int t = 0; t < NSLOT; ++t) {
      float s = 0.f;
      #pragma unroll
      for (int b = 0; b < REPL; ++b) s += ws[(b << 6) + t];
      fin[t] = s;
    }
    const float rec_loss = fin[0] / fin[1];
    const float kl_loss  = -0.5f * fin[4] / nz;
    const float cls_loss = -fin[5] / nc;
    const float inv_mexp = 1.f / fin[3];
    float fp = 0.f;
    #pragma unroll
    for (int v = 0; v < VB; ++v)
      fp += fmaxf(0.f, fin[6 + v] * inv_mexp - freqs[v]);
    out[0] = rec_loss + 0.1f * kl_loss + 2.f * cls_loss
           + 0.2f * fin[2] + 0.5f * fp;
  }
}

extern "C" void kernel_launch(void* const* d_in, const int* in_sizes, int n_in,
                              void* d_out, int out_size, void* d_ws, size_t ws_size,
                              hipStream_t stream) {
  const float* x   = (const float*)d_in[0];
  const float* rec = (const float*)d_in[1];
  const float* zm  = (const float*)d_in[2];
  const float* zlv = (const float*)d_in[3];
  const float* cs  = (const float*)d_in[4];
  float* out = (float*)d_out;
  float* ws  = (float*)d_ws;

  const int nrows = in_sizes[0] / (LL * VB);     // B
  const int nz    = in_sizes[2];                 // B * LATENT
  const int nc    = in_sizes[4];                 // B

  int nblocks = (nrows + 3) / 4;                 // 1 row per wave
  if (nblocks < 1) nblocks = 1;

  hipMemsetAsync(d_ws, 0, REPL * 64 * sizeof(float), stream);
  vae_main<<<nblocks, 256, 0, stream>>>(x, rec, zm, zlv, cs, ws,
                                        nrows, nz, nc, nblocks);
  vae_finalize<<<1, 64, 0, stream>>>(ws, out, (float)nz, (float)nc);
}

// Round 6
// 157.423 us; speedup vs baseline: 7.6330x; 1.1489x over previous
//
#include <hip/hip_runtime.h>
#include <math.h>

#define VB 28
#define LL 64
#define PAD_TOK 26
#define EOS_TOK 27
#define NSLOT 34   // 0 loss,1 mask,2 consec,3 mexp,4 kl,5 cls,6..33 vocab
#define REPL 8     // replicated atomic banks
#define RPW 4      // rows per wave

// (k+1)^2.5 table. MUST be a constexpr VARIABLE (mandatory compile-time init):
// round-4 lesson — a constexpr function in runtime context was emitted as
// runtime f64 Newton code (72% VALUBusy, 20x slowdown).
constexpr double csqrt_(double x) {
  double g = x > 1.0 ? x : 1.0;
  for (int i = 0; i < 60; ++i) g = 0.5 * (g + x / g);
  return g;
}
struct WTab { float w[64]; };
constexpr WTab make_wtab() {
  WTab t{};
  for (int k = 0; k < 64; ++k) {
    double n = (double)(k + 1);
    t.w[k] = (float)(n * n * csqrt_(n));   // (k+1)^2.5
  }
  return t;
}
constexpr WTab WTAB = make_wtab();

__device__ __forceinline__ float wave_red(float v) {
  #pragma unroll
  for (int o = 32; o > 0; o >>= 1) v += __shfl_down(v, o, 64);
  return v;
}

// ws layout: slot t, replica b at float index t*(REPL*32) + b*32
// -> every (t,b) owns its own 128-B cache line (no same-line serialization).
__global__ __launch_bounds__(256, 2) void vae_main(
    const float* __restrict__ x, const float* __restrict__ rec,
    const float* __restrict__ zm, const float* __restrict__ zlv,
    const float* __restrict__ cs, float* __restrict__ ws,
    int nrows, int nz, int nc, int nblocks) {
  __shared__ float adj_s[4][128];
  __shared__ float red[4][NSLOT];
  const int lane = threadIdx.x & 63;
  const int wid  = threadIdx.x >> 6;
  adj_s[wid][64 + lane] = 0.f;   // zero pad; reads reach at most index 125
  __builtin_amdgcn_wave_barrier();

  float loss_acc = 0.f, mask_cnt = 0.f, mexp_cnt = 0.f;
  float consec0 = 0.f, consec1 = 0.f;
  float vocab[VB];
  #pragma unroll
  for (int v = 0; v < VB; ++v) vocab[v] = 0.f;

  const int wave_id = blockIdx.x * 4 + wid;
  const int row0 = wave_id * RPW;

  // register double-buffer: prefetch row i+1 while processing row i
  float4 xa[7], ra[7];
  {
    const int row = row0;
    if (row < nrows) {
      const size_t base = ((size_t)row * LL + lane) * VB;
      const float4* xp = reinterpret_cast<const float4*>(x + base);
      const float4* rp = reinterpret_cast<const float4*>(rec + base);
      #pragma unroll
      for (int i = 0; i < 7; ++i) { xa[i] = xp[i]; ra[i] = rp[i]; }
    }
  }

  #pragma unroll
  for (int it = 0; it < RPW; ++it) {
    const int row = row0 + it;
    if (row >= nrows) break;

    float4 xb[7], rb[7];
    const int nrow = row + 1;
    const bool pf = (it + 1 < RPW) && (nrow < nrows);
    if (pf) {
      const size_t base = ((size_t)nrow * LL + lane) * VB;
      const float4* xp = reinterpret_cast<const float4*>(x + base);
      const float4* rp = reinterpret_cast<const float4*>(rec + base);
      #pragma unroll
      for (int i = 0; i < 7; ++i) { xb[i] = xp[i]; rb[i] = rp[i]; }
    }

    // ---- process current row from registers ----
    float r[VB];
    float best = -INFINITY, pt = 0.f;
    int tgt = 0;
    #pragma unroll
    for (int i = 0; i < 7; ++i) {
      const float4 xq = xa[i];
      const float4 rq = ra[i];
      r[i*4+0] = rq.x; r[i*4+1] = rq.y; r[i*4+2] = rq.z; r[i*4+3] = rq.w;
      if (xq.x > best) { best = xq.x; tgt = i*4+0; pt = rq.x; }
      if (xq.y > best) { best = xq.y; tgt = i*4+1; pt = rq.y; }
      if (xq.z > best) { best = xq.z; tgt = i*4+2; pt = rq.z; }
      if (xq.w > best) { best = xq.w; tgt = i*4+3; pt = rq.w; }
    }
    const float mask = (tgt != PAD_TOK) ? 1.f : 0.f;
    const float mexp = (tgt != PAD_TOK && tgt != EOS_TOK) ? 1.f : 0.f;
    loss_acc += -__logf(fminf(fmaxf(pt, 1e-7f), 1.f)) * mask;
    mask_cnt += mask;
    mexp_cnt += mexp;
    #pragma unroll
    for (int v = 0; v < VB; ++v) vocab[v] += r[v] * mexp;

    // adjacent[j] = dot(recon[:,j], recon[:,j+1]) * (target[j+1] != PAD)
    float adj = 0.f;
    #pragma unroll
    for (int v = 0; v < VB; ++v) adj += r[v] * __shfl_down(r[v], 1, 64);
    const int tgt_next = __shfl_down(tgt, 1, 64);
    adj = (lane < 63 && tgt_next != PAD_TOK) ? adj : 0.f;

    // stage adjacent in this wave's LDS row; wave_barrier = compiler fence
    // (round-3 bug: per-thread alias analysis hoists reads past the write)
    __builtin_amdgcn_wave_barrier();
    adj_s[wid][lane] = adj;
    __builtin_amdgcn_wave_barrier();

    // lane j: sum_k (k+1)^2.5 * prod(adj[j..j+k]); pad zeros kill windows
    // crossing the end; underflowed products stay exactly 0 (harmless).
    const float* ap = &adj_s[wid][lane];
    float p = adj;
    consec0 += p;                      // k=0, weight 1
    #pragma unroll
    for (int k = 1; k <= 62; k += 2) {
      p *= ap[k];
      consec1 += WTAB.w[k] * p;
      if (k + 1 <= 62) {
        p *= ap[k + 1];
        consec0 += WTAB.w[k + 1] * p;
      }
    }
    __builtin_amdgcn_wave_barrier();   // next row's write must not pass reads

    if (pf) {
      #pragma unroll
      for (int i = 0; i < 7; ++i) { xa[i] = xb[i]; ra[i] = rb[i]; }
    }
  }
  float consec_acc = consec0 + consec1;

  // KL + classifier terms, grid-strided over all threads
  const int gid = blockIdx.x * 256 + threadIdx.x;
  const int gstride = nblocks * 256;
  float kl = 0.f, cl = 0.f;
  for (int i = gid; i < nz; i += gstride) {
    const float m = zm[i], lv = zlv[i];
    kl += 1.f + lv - m * m - __expf(lv);
  }
  for (int i = gid; i < nc; i += gstride) cl += __logf(cs[i] + 1e-7f);

  loss_acc   = wave_red(loss_acc);
  mask_cnt   = wave_red(mask_cnt);
  consec_acc = wave_red(consec_acc);
  mexp_cnt   = wave_red(mexp_cnt);
  kl         = wave_red(kl);
  cl         = wave_red(cl);
  #pragma unroll
  for (int v = 0; v < VB; ++v) vocab[v] = wave_red(vocab[v]);

  if (lane == 0) {
    red[wid][0] = loss_acc; red[wid][1] = mask_cnt;
    red[wid][2] = consec_acc; red[wid][3] = mexp_cnt;
    red[wid][4] = kl; red[wid][5] = cl;
    #pragma unroll
    for (int v = 0; v < VB; ++v) red[wid][6 + v] = vocab[v];
  }
  __syncthreads();
  if (threadIdx.x < NSLOT) {   // fire-and-forget; one line per (slot,replica)
    const int t = threadIdx.x;
    const int b = blockIdx.x & (REPL - 1);
    atomicAdd(&ws[t * (REPL * 32) + b * 32],
              red[0][t] + red[1][t] + red[2][t] + red[3][t]);
  }
}

__global__ void vae_finalize(const float* __restrict__ ws, float* __restrict__ out,
                             float nz, float nc) {
  if (threadIdx.x == 0 && blockIdx.x == 0) {
    const float freqs[VB] = {0.0817f,0.0149f,0.0278f,0.0425f,0.127f,0.0223f,
      0.0202f,0.0609f,0.0697f,0.0015f,0.0077f,0.0403f,0.0241f,0.0675f,0.0751f,
      0.0193f,0.001f,0.0599f,0.0633f,0.0906f,0.0276f,0.0098f,0.0236f,0.0015f,
      0.0197f,0.0007f,0.f,0.f};
    float fin[NSLOT];
    #pragma unroll
    for (int t = 0; t < NSLOT; ++t) {
      float s = 0.f;
      #pragma unroll
      for (int b = 0; b < REPL; ++b) s += ws[t * (REPL * 32) + b * 32];
      fin[t] = s;
    }
    const float rec_loss = fin[0] / fin[1];
    const float kl_loss  = -0.5f * fin[4] / nz;
    const float cls_loss = -fin[5] / nc;
    const float inv_mexp = 1.f / fin[3];
    float fp = 0.f;
    #pragma unroll
    for (int v = 0; v < VB; ++v)
      fp += fmaxf(0.f, fin[6 + v] * inv_mexp - freqs[v]);
    out[0] = rec_loss + 0.1f * kl_loss + 2.f * cls_loss
           + 0.2f * fin[2] + 0.5f * fp;
  }
}

extern "C" void kernel_launch(void* const* d_in, const int* in_sizes, int n_in,
                              void* d_out, int out_size, void* d_ws, size_t ws_size,
                              hipStream_t stream) {
  const float* x   = (const float*)d_in[0];
  const float* rec = (const float*)d_in[1];
  const float* zm  = (const float*)d_in[2];
  const float* zlv = (const float*)d_in[3];
  const float* cs  = (const float*)d_in[4];
  float* out = (float*)d_out;
  float* ws  = (float*)d_ws;

  const int nrows = in_sizes[0] / (LL * VB);     // B
  const int nz    = in_sizes[2];                 // B * LATENT
  const int nc    = in_sizes[4];                 // B

  int nblocks = (nrows + 4 * RPW - 1) / (4 * RPW);   // 4 rows per wave
  if (nblocks < 1) nblocks = 1;

  hipMemsetAsync(d_ws, 0, NSLOT * REPL * 32 * sizeof(float), stream);
  vae_main<<<nblocks, 256, 0, stream>>>(x, rec, zm, zlv, cs, ws,
                                        nrows, nz, nc, nblocks);
  vae_finalize<<<1, 64, 0, stream>>>(ws, out, (float)nz, (float)nc);
}